// Round 14
// baseline (303.622 us; speedup 1.0000x reference)
//
#include <hip/hip_runtime.h>
#include <hip/hip_bf16.h>

#define N_NODES 50000
#define N_EDGES 1600000
#define NBUCK 98              // ceil(50000/512) buckets of 512 nodes
#define EPB 4096              // edges per binning block
#define NB_A ((N_EDGES + EPB - 1) / EPB)   // 391
#define CAP 20480             // per-bucket capacity (expected 16384 +- 128)

typedef short bf16x8 __attribute__((ext_vector_type(8)));
typedef float f32x4  __attribute__((ext_vector_type(4)));

__device__ __forceinline__ float bf16_raw_to_f32(unsigned short u) {
    return __uint_as_float(((unsigned)u) << 16);
}
__device__ __forceinline__ unsigned short f32_to_bf16_raw(float v) {
    unsigned u = __float_as_uint(v);
    return (unsigned short)((u + 0x7fffu + ((u >> 16) & 1u)) >> 16);
}
__device__ __forceinline__ float load_elem(const void* p, size_t i, int f) {
    if (f) return ((const float*)p)[i];
    return bf16_raw_to_f32(((const unsigned short*)p)[i]);
}
__device__ __forceinline__ void unpack8(uint4 u, float* f) {
    f[0] = __uint_as_float(u.x << 16);
    f[1] = __uint_as_float(u.x & 0xffff0000u);
    f[2] = __uint_as_float(u.y << 16);
    f[3] = __uint_as_float(u.y & 0xffff0000u);
    f[4] = __uint_as_float(u.z << 16);
    f[5] = __uint_as_float(u.z & 0xffff0000u);
    f[6] = __uint_as_float(u.w << 16);
    f[7] = __uint_as_float(u.w & 0xffff0000u);
}

// ---- dtype probe (verified R4): flag=1 -> fp32 storage.
// Also pre-arms bucket cursors (b*CAP) and zeroes the norm-max slots.
__global__ void detect_dtype_kernel(const unsigned short* __restrict__ w1raw,
                                    int* __restrict__ flag, int* __restrict__ bcur,
                                    unsigned* __restrict__ n1max,
                                    unsigned* __restrict__ n2max) {
    __shared__ float red[256];
    int t = threadIdx.x;
    if (t < NBUCK) bcur[t] = t * CAP;
    if (t < 8) n1max[t] = 0u;
    if (t == 8) n2max[0] = 0u;
    float mx = 0.f;
    for (int i = t * 2; i < 16384; i += 512) {
        float v = fabsf(bf16_raw_to_f32(w1raw[i]));
        if (!isnan(v)) mx = fmaxf(mx, v);
    }
    red[t] = mx;
    __syncthreads();
    for (int s = 128; s > 0; s >>= 1) {
        if (t < s) red[t] = fmaxf(red[t], red[t + s]);
        __syncthreads();
    }
    if (t == 0) flag[0] = (red[0] > 1e4f) ? 1 : 0;
}

// ---- prep: W1T[n][k] (128x136 bf16), W2T[n][k] (64x136 bf16) ----
#define WPAD 136
__global__ void prep_kernel(const void* __restrict__ W1, const void* __restrict__ W2,
                            unsigned short* __restrict__ W1T,
                            unsigned short* __restrict__ W2T,
                            const int* __restrict__ flag) {
    const int f = *flag;
    int bid = blockIdx.x, tid = threadIdx.x;
    if (bid < 8) {
        int n = bid * 16 + (tid & 15);
        int kb = (tid >> 4) * 8;
        for (int j = 0; j < 8; ++j)
            W1T[n * WPAD + kb + j] = f32_to_bf16_raw(load_elem(W1, (size_t)(kb + j) * 128 + n, f));
    } else {
        int n = (bid - 8) * 16 + (tid & 15);
        int kb = (tid >> 4) * 8;
        for (int j = 0; j < 8; ++j)
            W2T[n * WPAD + kb + j] = f32_to_bf16_raw(load_elem(W2, (size_t)(kb + j) * 64 + n, f));
    }
}

// ============ single-pass binned CSR build ============
// binA: blocks reserve per-bucket space directly in fixed-capacity regions
// (bcur pre-armed at b*CAP) -> no pre-count pass needed.
__global__ void binA_kernel(const int* __restrict__ src, const int* __restrict__ dst,
                            int* __restrict__ bcur, unsigned* __restrict__ inter, int E) {
    __shared__ int hist[NBUCK], gbase[NBUCK], cur[NBUCK];
    int t = threadIdx.x;
    if (t < NBUCK) hist[t] = 0;
    __syncthreads();
    int e0 = blockIdx.x * EPB;
    for (int k = 0; k < 16; ++k) {
        int e = e0 + k * 256 + t;
        if (e < E) atomicAdd(&hist[dst[e] >> 9], 1);
    }
    __syncthreads();
    if (t < NBUCK) {
        int hv = hist[t];
        gbase[t] = hv ? atomicAdd(&bcur[t], hv) : 0;
        cur[t] = 0;
    }
    __syncthreads();
    for (int k = 0; k < 16; ++k) {
        int e = e0 + k * 256 + t;
        if (e < E) {
            int d = dst[e];
            int b = d >> 9;
            int off = atomicAdd(&cur[b], 1);
            inter[gbase[b] + off] = (unsigned)src[e] | ((unsigned)(d & 511) << 16);
        }
    }
}

// post-binA: exclusive scan of per-bucket counts (bcur[b]-b*CAP) -> bbase.
__global__ void bucket_scan_kernel(const int* __restrict__ bcur, int* __restrict__ bbase) {
    __shared__ int tmp[128];
    int t = threadIdx.x;
    int v = (t < NBUCK) ? (bcur[t] - t * CAP) : 0;
    tmp[t] = v;
    __syncthreads();
    for (int off = 1; off < 128; off <<= 1) {
        int x = (t >= off) ? tmp[t - off] : 0;
        __syncthreads();
        tmp[t] += x;
        __syncthreads();
    }
    if (t < NBUCK) bbase[t] = tmp[t] - v;
    if (t == NBUCK - 1) bbase[NBUCK] = tmp[t];
}

__global__ void binB_kernel(const unsigned* __restrict__ inter,
                            const int* __restrict__ bbase,
                            int* __restrict__ csr_src, int* __restrict__ start,
                            int N, int E) {
    int b = blockIdx.x;
    int node0 = b << 9;
    int inbase = b * CAP;
    int obase = bbase[b];
    int cnt = bbase[b + 1] - obase;
    __shared__ int hist[512];
    __shared__ int t2[256];
    int t = threadIdx.x;
    hist[t] = 0; hist[t + 256] = 0;
    __syncthreads();
    for (int e = t; e < cnt; e += 256) atomicAdd(&hist[inter[inbase + e] >> 16], 1);
    __syncthreads();
    int s0 = hist[2 * t], s1 = hist[2 * t + 1];
    t2[t] = s0 + s1;
    __syncthreads();
    for (int off = 1; off < 256; off <<= 1) {
        int x = (t >= off) ? t2[t - off] : 0;
        __syncthreads();
        t2[t] += x;
        __syncthreads();
    }
    int base = (t == 0) ? 0 : t2[t - 1];
    hist[2 * t] = base;
    hist[2 * t + 1] = base + s0;
    __syncthreads();
    int nodeCnt = min(512, N - node0);
    for (int i = t; i < nodeCnt; i += 256) start[node0 + i] = obase + hist[i];
    if (b == NBUCK - 1 && t == 0) start[N] = E;
    __syncthreads();
    for (int e = t; e < cnt; e += 256) {
        unsigned u = inter[inbase + e];
        int slot = obase + atomicAdd(&hist[u >> 16], 1);
        csr_src[slot] = (int)(u & 0xffffu);
    }
}

// ---- MFMA GEMM1 (R9-proven) ----
__global__ void gemm1_mfma_kernel(const void* __restrict__ h,
                                  const unsigned short* __restrict__ W1T,
                                  unsigned short* __restrict__ feat1, int N,
                                  const int* __restrict__ flag) {
    const int f = *flag;
    int lane = threadIdx.x & 63;
    int rbase = blockIdx.x * 64 + (threadIdx.x >> 6) * 16;
    int arow = rbase + (lane & 15);
    int arowc = min(arow, N - 1);
    int kb0 = (lane >> 4) * 8;

    f32x4 acc[8];
#pragma unroll
    for (int t = 0; t < 8; ++t) acc[t] = (f32x4){0.f, 0.f, 0.f, 0.f};

#pragma unroll
    for (int ks = 0; ks < 4; ++ks) {
        int kb = ks * 32 + kb0;
        bf16x8 afrag;
        if (f == 0) {
            afrag = *(const bf16x8*)((const unsigned short*)h + (size_t)arowc * 128 + kb);
        } else {
            const float* hp = (const float*)h + (size_t)arowc * 128 + kb;
#pragma unroll
            for (int j = 0; j < 8; ++j) afrag[j] = (short)f32_to_bf16_raw(hp[j]);
        }
#pragma unroll
        for (int t = 0; t < 8; ++t) {
            int n = t * 16 + (lane & 15);
            bf16x8 bfrag = *(const bf16x8*)(W1T + n * WPAD + kb);
            acc[t] = __builtin_amdgcn_mfma_f32_16x16x32_bf16(afrag, bfrag, acc[t], 0, 0, 0);
        }
    }
    int orow0 = rbase + (lane >> 4) * 4;
    int col = lane & 15;
#pragma unroll
    for (int t = 0; t < 8; ++t)
#pragma unroll
        for (int r = 0; r < 4; ++r) {
            int row = orow0 + r;
            if (row < N)
                feat1[(size_t)row * 128 + t * 16 + col] = f32_to_bf16_raw(acc[t][r]);
        }
}

// ---- MFMA GEMM2 (R9-proven) ----
__global__ void gemm2_mfma_kernel(const unsigned short* __restrict__ agg1e,
                                  const unsigned short* __restrict__ W2T,
                                  unsigned short* __restrict__ feat2, int N) {
    int lane = threadIdx.x & 63;
    int rbase = blockIdx.x * 64 + (threadIdx.x >> 6) * 16;
    int arow = rbase + (lane & 15);
    int arowc = min(arow, N - 1);
    int kb0 = (lane >> 4) * 8;

    f32x4 acc[4];
#pragma unroll
    for (int t = 0; t < 4; ++t) acc[t] = (f32x4){0.f, 0.f, 0.f, 0.f};

#pragma unroll
    for (int ks = 0; ks < 4; ++ks) {
        int kb = ks * 32 + kb0;
        bf16x8 afrag = *(const bf16x8*)(agg1e + (size_t)arowc * 128 + kb);
#pragma unroll
        for (int t = 0; t < 4; ++t) {
            int n = t * 16 + (lane & 15);
            bf16x8 bfrag = *(const bf16x8*)(W2T + n * WPAD + kb);
            acc[t] = __builtin_amdgcn_mfma_f32_16x16x32_bf16(afrag, bfrag, acc[t], 0, 0, 0);
        }
    }
    int orow0 = rbase + (lane >> 4) * 4;
    int col = lane & 15;
#pragma unroll
    for (int t = 0; t < 4; ++t)
#pragma unroll
        for (int r = 0; r < 4; ++r) {
            int row = orow0 + r;
            if (row < N)
                feat2[(size_t)row * 64 + t * 16 + col] = f32_to_bf16_raw(acc[t][r]);
        }
}

// ---- per-(node,head) L2 norms of feat1 + per-head global max (block-reduced)
__global__ void norms1_kernel(const unsigned short* __restrict__ feat1,
                              float* __restrict__ n1, unsigned* __restrict__ n1max,
                              int N) {
    __shared__ unsigned bmax[8];
    if (threadIdx.x < 8) bmax[threadIdx.x] = 0u;
    __syncthreads();
    int gid = blockIdx.x * 256 + threadIdx.x;
    if (gid < N * 8) {
        int v = gid >> 3, hd = gid & 7;
        const uint4* p = (const uint4*)(feat1 + (size_t)v * 128 + hd * 16);
        float f[8]; float s = 0.f;
        unpack8(p[0], f);
#pragma unroll
        for (int j = 0; j < 8; ++j) s += f[j] * f[j];
        unpack8(p[1], f);
#pragma unroll
        for (int j = 0; j < 8; ++j) s += f[j] * f[j];
        float n = sqrtf(s);
        n1[gid] = n;
        atomicMax(&bmax[hd], __float_as_uint(n));   // n>=0: uint order == float order
    }
    __syncthreads();
    if (threadIdx.x < 8 && bmax[threadIdx.x]) atomicMax(&n1max[threadIdx.x], bmax[threadIdx.x]);
}

// ---- per-node L2 norm of feat2 + global max ----
__global__ void norms2_kernel(const unsigned short* __restrict__ feat2,
                              float* __restrict__ n2, unsigned* __restrict__ n2max,
                              int N) {
    __shared__ unsigned bmax;
    if (threadIdx.x == 0) bmax = 0u;
    __syncthreads();
    int v = blockIdx.x * 256 + threadIdx.x;
    if (v < N) {
        const uint4* p = (const uint4*)(feat2 + (size_t)v * 64);
        float s = 0.f;
#pragma unroll
        for (int q = 0; q < 8; ++q) {
            float f[8]; unpack8(p[q], f);
#pragma unroll
            for (int j = 0; j < 8; ++j) s += f[j] * f[j];
        }
        float n = sqrtf(s);
        n2[v] = n;
        atomicMax(&bmax, __float_as_uint(n));
    }
    __syncthreads();
    if (threadIdx.x == 0 && bmax) atomicMax(n2max, bmax);
}

// ======= layer 1 fused GAT: wave = 1 dst; 4 groups x 16 lanes =======
// R14: fixed shift M = ||fd_h||*max||f_h||/4 >= all scores (Cauchy-Schwarz).
// Equivalent to the proven online update initialized with m=M (m never
// updates): w=exp(sc-M), a+=w*fv, l+=w; common e^(m-M) factor cancels in a/l.
__global__ void gat1_kernel(const unsigned short* __restrict__ feat1,
                            const int* __restrict__ csr_src,
                            const int* __restrict__ start,
                            const float* __restrict__ n1,
                            const float* __restrict__ n1max,
                            unsigned short* __restrict__ agg1e, int N) {
    int wave = blockIdx.x * 4 + (threadIdx.x >> 6);
    if (wave >= N) return;
    int lane = threadIdx.x & 63;
    int grp = lane >> 4, gl = lane & 15;
    int hd = gl >> 1;
    const char* fb = (const char*)feat1;       // uniform base; row = 256 B
    unsigned loff = (unsigned)gl << 4;
    float fd[8];
    unpack8(*(const uint4*)(fb + (((unsigned)wave << 8) + loff)), fd);
    float M = 0.25f * n1[wave * 8 + hd] * n1max[hd];

    float l = 0.f, a[8];
#pragma unroll
    for (int j = 0; j < 8; ++j) a[j] = 0.f;

    int e0 = start[wave], e1 = start[wave + 1];
    int base = e0;
    for (; base + 8 <= e1; base += 8) {
        int s0 = csr_src[base + grp];
        int s1 = csr_src[base + 4 + grp];
        uint4 u0 = *(const uint4*)(fb + (((unsigned)s0 << 8) + loff));
        uint4 u1 = *(const uint4*)(fb + (((unsigned)s1 << 8) + loff));
        float f0[8], f1[8];
        unpack8(u0, f0); unpack8(u1, f1);
        float p0 = 0.f, p1 = 0.f;
#pragma unroll
        for (int j = 0; j < 8; ++j) { p0 += fd[j] * f0[j]; p1 += fd[j] * f1[j]; }
        p0 += __shfl_xor(p0, 1);               // 16-dim head dot
        p1 += __shfl_xor(p1, 1);
        float w0 = __expf(fmaf(p0, 0.25f, -M));
        float w1 = __expf(fmaf(p1, 0.25f, -M));
#pragma unroll
        for (int j = 0; j < 8; ++j) a[j] = fmaf(w0, f0[j], a[j]);
#pragma unroll
        for (int j = 0; j < 8; ++j) a[j] = fmaf(w1, f1[j], a[j]);
        l += w0 + w1;
    }
    for (; base < e1; base += 4) {
        int ed = base + grp;
        bool act = ed < e1;
        int s = act ? csr_src[ed] : 0;
        uint4 u = *(const uint4*)(fb + (((unsigned)s << 8) + loff));
        float fv[8]; unpack8(u, fv);
        float p = 0.f;
#pragma unroll
        for (int j = 0; j < 8; ++j) p += fd[j] * fv[j];
        p += __shfl_xor(p, 1);
        if (act) {
            float w = __expf(fmaf(p, 0.25f, -M));
#pragma unroll
            for (int j = 0; j < 8; ++j) a[j] = fmaf(w, fv[j], a[j]);
            l += w;
        }
    }
    // merge the 4 group-partials: same M -> plain adds
#pragma unroll
    for (int off = 16; off <= 32; off <<= 1) {
#pragma unroll
        for (int j = 0; j < 8; ++j) a[j] += __shfl_xor(a[j], off);
        l += __shfl_xor(l, off);
    }
    if (grp == 0) {
        float rcp = 1.f / fmaxf(l, 1e-9f);
        float v[8];
#pragma unroll
        for (int j = 0; j < 8; ++j) {
            float x = a[j] * rcp;
            v[j] = (x > 0.f) ? x : expm1f(x);   // ELU fused
        }
        uint4 pk;
        pk.x = (unsigned)f32_to_bf16_raw(v[0]) | ((unsigned)f32_to_bf16_raw(v[1]) << 16);
        pk.y = (unsigned)f32_to_bf16_raw(v[2]) | ((unsigned)f32_to_bf16_raw(v[3]) << 16);
        pk.z = (unsigned)f32_to_bf16_raw(v[4]) | ((unsigned)f32_to_bf16_raw(v[5]) << 16);
        pk.w = (unsigned)f32_to_bf16_raw(v[6]) | ((unsigned)f32_to_bf16_raw(v[7]) << 16);
        *(uint4*)(agg1e + (size_t)wave * 128 + gl * 8) = pk;
    }
}

// ======= layer 2 fused GAT: wave = 1 dst; 8 groups x 8 lanes =======
__global__ void gat2_kernel(const unsigned short* __restrict__ feat2,
                            const int* __restrict__ csr_src,
                            const int* __restrict__ start,
                            const float* __restrict__ n2,
                            const float* __restrict__ n2max,
                            void* __restrict__ out, int N,
                            const int* __restrict__ flag) {
    int wave = blockIdx.x * 4 + (threadIdx.x >> 6);
    if (wave >= N) return;
    int lane = threadIdx.x & 63;
    int grp = lane >> 3, gl = lane & 7;
    const int f = *flag;
    const char* fb = (const char*)feat2;       // uniform base; row = 128 B
    unsigned loff = (unsigned)gl << 4;
    float fd[8];
    unpack8(*(const uint4*)(fb + (((unsigned)wave << 7) + loff)), fd);
    float M = 0.125f * n2[wave] * n2max[0];

    float l = 0.f, a[8];
#pragma unroll
    for (int j = 0; j < 8; ++j) a[j] = 0.f;

    int e0 = start[wave], e1 = start[wave + 1];
    int base = e0;
    for (; base + 16 <= e1; base += 16) {
        int s0 = csr_src[base + grp];
        int s1 = csr_src[base + 8 + grp];
        uint4 u0 = *(const uint4*)(fb + (((unsigned)s0 << 7) + loff));
        uint4 u1 = *(const uint4*)(fb + (((unsigned)s1 << 7) + loff));
        float f0[8], f1[8];
        unpack8(u0, f0); unpack8(u1, f1);
        float p0 = 0.f, p1 = 0.f;
#pragma unroll
        for (int j = 0; j < 8; ++j) { p0 += fd[j] * f0[j]; p1 += fd[j] * f1[j]; }
        p0 += __shfl_xor(p0, 1); p1 += __shfl_xor(p1, 1);
        p0 += __shfl_xor(p0, 2); p1 += __shfl_xor(p1, 2);
        p0 += __shfl_xor(p0, 4); p1 += __shfl_xor(p1, 4);   // full 64-dim dot
        float w0 = __expf(fmaf(p0, 0.125f, -M));
        float w1 = __expf(fmaf(p1, 0.125f, -M));
#pragma unroll
        for (int j = 0; j < 8; ++j) a[j] = fmaf(w0, f0[j], a[j]);
#pragma unroll
        for (int j = 0; j < 8; ++j) a[j] = fmaf(w1, f1[j], a[j]);
        l += w0 + w1;
    }
    for (; base < e1; base += 8) {
        int ed = base + grp;
        bool act = ed < e1;
        int s = act ? csr_src[ed] : 0;
        uint4 u = *(const uint4*)(fb + (((unsigned)s << 7) + loff));
        float fv[8]; unpack8(u, fv);
        float p = 0.f;
#pragma unroll
        for (int j = 0; j < 8; ++j) p += fd[j] * fv[j];
        p += __shfl_xor(p, 1);
        p += __shfl_xor(p, 2);
        p += __shfl_xor(p, 4);
        if (act) {
            float w = __expf(fmaf(p, 0.125f, -M));
#pragma unroll
            for (int j = 0; j < 8; ++j) a[j] = fmaf(w, fv[j], a[j]);
            l += w;
        }
    }
#pragma unroll
    for (int off = 8; off <= 32; off <<= 1) {
#pragma unroll
        for (int j = 0; j < 8; ++j) a[j] += __shfl_xor(a[j], off);
        l += __shfl_xor(l, off);
    }
    if (grp == 0) {
        float rcp = 1.f / fmaxf(l, 1e-9f);
        float v[8];
#pragma unroll
        for (int j = 0; j < 8; ++j) v[j] = a[j] * rcp;
        if (f) {
            float* op = (float*)out + (size_t)wave * 64 + gl * 8;
            *(float4*)(op)     = (float4){v[0], v[1], v[2], v[3]};
            *(float4*)(op + 4) = (float4){v[4], v[5], v[6], v[7]};
        } else {
            uint4 pk;
            pk.x = (unsigned)f32_to_bf16_raw(v[0]) | ((unsigned)f32_to_bf16_raw(v[1]) << 16);
            pk.y = (unsigned)f32_to_bf16_raw(v[2]) | ((unsigned)f32_to_bf16_raw(v[3]) << 16);
            pk.z = (unsigned)f32_to_bf16_raw(v[4]) | ((unsigned)f32_to_bf16_raw(v[5]) << 16);
            pk.w = (unsigned)f32_to_bf16_raw(v[6]) | ((unsigned)f32_to_bf16_raw(v[7]) << 16);
            *(uint4*)((unsigned short*)out + (size_t)wave * 64 + gl * 8) = pk;
        }
    }
}

extern "C" void kernel_launch(void* const* d_in, const int* in_sizes, int n_in,
                              void* d_out, int out_size, void* d_ws, size_t ws_size,
                              hipStream_t stream) {
    const void* h  = d_in[0];
    const void* W1 = d_in[1];
    const void* W2 = d_in[2];
    const int* src = (const int*)d_in[3];
    const int* dst = (const int*)d_in[4];

    float* ws = (float*)d_ws;
    // Layout (4-byte words), peak ~11.36M words = 45.5 MB:
    //   [0,     3.2M)   feat1 [N,128] bf16       (later: feat2 [N,64] bf16)
    //   [3.2M,  4.8M)   agg1e [N,128] bf16 (ELU applied)
    //   [6.4M,  8.41M)  inter: 98 buckets x CAP uints
    //   [8.5M,  8.9M)   n1 [N,8] float
    //   [8.9M,  8.95M)  n2 [N] float
    //   [9.6M, 11.2M)   csr_src [E] int
    //   [11.2M,11.26M)  start [N+1] int
    //   [11.33M] flag; [11.332M] bbase[99]; [11.333M] bcur[98]
    //   [11.334M] n1max[8]; [11.3341M] n2max[1]
    //   [11.34M..] W1T; [11.35M..] W2T
    unsigned short* feat1 = (unsigned short*)ws;
    unsigned short* agg1e = (unsigned short*)(ws + 3200000);
    unsigned short* feat2 = (unsigned short*)ws;      // after feat1 dead
    unsigned* inter       = (unsigned*)(ws + 6400000);
    float* n1             = ws + 8500000;
    float* n2             = ws + 8900000;
    int*   csr_src        = (int*)(ws + 9600000);
    int*   start          = (int*)(ws + 11200000);
    int*   flag           = (int*)(ws + 11330000);
    int*   bbase          = (int*)(ws + 11332000);
    int*   bcur           = (int*)(ws + 11333000);
    unsigned* n1max       = (unsigned*)(ws + 11334000);
    unsigned* n2max       = (unsigned*)(ws + 11334016);
    unsigned short* W1T   = (unsigned short*)(ws + 11340000);
    unsigned short* W2T   = (unsigned short*)(ws + 11350000);

    detect_dtype_kernel<<<1, 256, 0, stream>>>((const unsigned short*)W1, flag, bcur, n1max, n2max);
    prep_kernel<<<12, 256, 0, stream>>>(W1, W2, W1T, W2T, flag);

    // ---- single-pass binned CSR build (by dst), storing src ids ----
    binA_kernel<<<NB_A, 256, 0, stream>>>(src, dst, bcur, inter, N_EDGES);
    bucket_scan_kernel<<<1, 128, 0, stream>>>(bcur, bbase);
    binB_kernel<<<NBUCK, 256, 0, stream>>>(inter, bbase, csr_src, start, N_NODES, N_EDGES);

    gemm1_mfma_kernel<<<(N_NODES + 63) / 64, 256, 0, stream>>>(h, W1T, feat1, N_NODES, flag);
    norms1_kernel<<<(N_NODES * 8 + 255) / 256, 256, 0, stream>>>(feat1, n1, n1max, N_NODES);
    gat1_kernel<<<(N_NODES + 3) / 4, 256, 0, stream>>>(feat1, csr_src, start, n1, (const float*)n1max, agg1e, N_NODES);
    gemm2_mfma_kernel<<<(N_NODES + 63) / 64, 256, 0, stream>>>(agg1e, W2T, feat2, N_NODES);
    norms2_kernel<<<(N_NODES + 255) / 256, 256, 0, stream>>>(feat2, n2, n2max, N_NODES);
    gat2_kernel<<<(N_NODES + 3) / 4, 256, 0, stream>>>(feat2, csr_src, start, n2, (const float*)n2max, d_out, N_NODES, flag);
}